// Round 1
// baseline (483.140 us; speedup 1.0000x reference)
//
#include <hip/hip_runtime.h>

// SGConv regression, commuted: out = mean_g( S^K (x @ W) + b )
// N=100000 nodes, E=1600000 edges, F=128, K=3 hops, G=512 graphs.

#define BLK 256

__global__ void k_deg_init(float* __restrict__ deg, int n) {
    int i = blockIdx.x * blockDim.x + threadIdx.x;
    if (i < n) deg[i] = 1.0f;  // self-loop contribution
}

__global__ void k_deg_edges(const int* __restrict__ col, float* __restrict__ deg, int e) {
    int i = blockIdx.x * blockDim.x + threadIdx.x;
    int stride = gridDim.x * blockDim.x;
    for (; i < e; i += stride) atomicAdd(&deg[col[i]], 1.0f);
}

__global__ void k_dis(float* __restrict__ deg, int n) {
    int i = blockIdx.x * blockDim.x + threadIdx.x;
    if (i < n) deg[i] = rsqrtf(deg[i]);  // deg >= 1 always (self-loops)
}

// wave-per-row dot product: y[r] = x[r,:]·W; z[r] = dis[r]*y[r]; t[r] = z[r]
__global__ void k_y(const float* __restrict__ x, const float* __restrict__ W,
                    const float* __restrict__ dis,
                    float* __restrict__ z, float* __restrict__ t, int n) {
    int wave = blockIdx.x * (BLK / 64) + (threadIdx.x >> 6);
    int lane = threadIdx.x & 63;
    if (wave >= n) return;
    const float2* xr = (const float2*)(x + (size_t)wave * 128);
    const float2* wr = (const float2*)W;
    float2 xv = xr[lane];
    float2 wv = wr[lane];
    float s = xv.x * wv.x + xv.y * wv.y;
    #pragma unroll
    for (int off = 32; off; off >>= 1) s += __shfl_down(s, off);
    if (lane == 0) {
        float zz = dis[wave] * s;
        z[wave] = zz;
        t[wave] = zz;
    }
}

// one propagation hop (non-self edges): t[col] += z[row]
__global__ void k_edges(const int* __restrict__ row, const int* __restrict__ col,
                        const float* __restrict__ z, float* __restrict__ t, int e) {
    int i = blockIdx.x * blockDim.x + threadIdx.x;
    int stride = gridDim.x * blockDim.x;
    for (; i < e; i += stride) {
        atomicAdd(&t[col[i]], z[row[i]]);
    }
}

// between hops: y_next = dis*t ; z = dis*y_next = dis^2*t ; t = z (self loop)
__global__ void k_post(const float* __restrict__ dis, float* __restrict__ z,
                       float* __restrict__ t, int n) {
    int i = blockIdx.x * blockDim.x + threadIdx.x;
    if (i < n) {
        float d = dis[i];
        float v = d * d * t[i];
        z[i] = v;
        t[i] = v;
    }
}

// segment sum/count over sorted batch vector, wave-uniform fast path
__global__ void k_reduce(const float* __restrict__ dis, const float* __restrict__ t,
                         const int* __restrict__ batch,
                         float* __restrict__ s, float* __restrict__ c, int n) {
    int i = blockIdx.x * blockDim.x + threadIdx.x;
    int lane = threadIdx.x & 63;
    float y = 0.0f;
    int g = -1;
    if (i < n) {
        y = dis[i] * t[i];  // final hop's y
        g = batch[i];
    }
    int g0 = __shfl(g, 0);
    if (__all(g == g0) && g0 >= 0) {
        float sum = y;
        #pragma unroll
        for (int off = 32; off; off >>= 1) sum += __shfl_down(sum, off);
        if (lane == 0) {
            atomicAdd(&s[g0], sum);
            atomicAdd(&c[g0], 64.0f);
        }
    } else if (g >= 0) {
        atomicAdd(&s[g], y);
        atomicAdd(&c[g], 1.0f);
    }
}

__global__ void k_final(const float* __restrict__ s, const float* __restrict__ c,
                        const float* __restrict__ b, float* __restrict__ out, int g) {
    int i = blockIdx.x * blockDim.x + threadIdx.x;
    if (i < g) out[i] = s[i] / fmaxf(c[i], 1.0f) + b[0];
}

extern "C" void kernel_launch(void* const* d_in, const int* in_sizes, int n_in,
                              void* d_out, int out_size, void* d_ws, size_t ws_size,
                              hipStream_t stream) {
    const float* x    = (const float*)d_in[0];   // [N,128]
    const float* W    = (const float*)d_in[1];   // [128,1]
    const float* b    = (const float*)d_in[2];   // [1]
    const int*   ei   = (const int*)d_in[3];     // [2,E]
    const int*   batch= (const int*)d_in[4];     // [N]
    float* out = (float*)d_out;                  // [G,1]

    const int N = in_sizes[0] / 128;
    const int E = in_sizes[3] / 2;
    const int G = out_size;

    const int* row = ei;        // edge_index[0]
    const int* col = ei + E;    // edge_index[1]

    // workspace layout (floats): dis[N] | z[N] | t[N] | s[G] | c[G]
    float* dis = (float*)d_ws;
    float* z   = dis + N;
    float* t   = z + N;
    float* s   = t + N;
    float* c   = s + G;

    // zero the per-graph accumulators (ws is poisoned before every call)
    hipMemsetAsync(s, 0, 2 * (size_t)G * sizeof(float), stream);

    int nbN = (N + BLK - 1) / BLK;
    int nbE = (E + BLK - 1) / BLK;

    // degree + dis
    k_deg_init<<<nbN, BLK, 0, stream>>>(dis, N);
    k_deg_edges<<<nbE, BLK, 0, stream>>>(col, dis, E);
    k_dis<<<nbN, BLK, 0, stream>>>(dis, N);

    // project to scalar first (linearity), init hop state
    int nbY = (N + (BLK / 64) - 1) / (BLK / 64);
    k_y<<<nbY, BLK, 0, stream>>>(x, W, dis, z, t, N);

    // K = 3 hops
    k_edges<<<nbE, BLK, 0, stream>>>(row, col, z, t, E);
    k_post<<<nbN, BLK, 0, stream>>>(dis, z, t, N);
    k_edges<<<nbE, BLK, 0, stream>>>(row, col, z, t, E);
    k_post<<<nbN, BLK, 0, stream>>>(dis, z, t, N);
    k_edges<<<nbE, BLK, 0, stream>>>(row, col, z, t, E);

    // segment mean over sorted batch + bias
    k_reduce<<<nbN, BLK, 0, stream>>>(dis, t, batch, s, c, N);
    k_final<<<(G + BLK - 1) / BLK, BLK, 0, stream>>>(s, c, b, out, G);
}